// Round 7
// baseline (335.588 us; speedup 1.0000x reference)
//
#include <hip/hip_runtime.h>
#include <math.h>

#define NB 2048
typedef float f32x4 __attribute__((ext_vector_type(4)));
typedef float f32x2 __attribute__((ext_vector_type(2)));

// pre[] float offsets (folded weights)
#define P_WAL 0
#define P_WBL 1024
#define P_WLBL 2048
#define P_WNAL 3072
#define P_WEFF 4096
#define P_BWA 4160
#define P_BWB 4176
#define P_BWL 4192
#define P_BWN 4208
#define P_C0  4224

// ws float offsets
#define WS_BNPART 4352
#define WS_COEF   135424

__device__ __forceinline__ unsigned short f2bf(float f) {
  unsigned int u = __float_as_uint(f);
  u += 0x7fffu + ((u >> 16) & 1u);
  return (unsigned short)(u >> 16);
}
__device__ __forceinline__ unsigned int pack2bf(float lo, float hi) {
  return (unsigned int)f2bf(lo) | ((unsigned int)f2bf(hi) << 16);
}
__device__ __forceinline__ float bflo(unsigned int u) { return __uint_as_float(u << 16); }
__device__ __forceinline__ float bfhi(unsigned int u) { return __uint_as_float(u & 0xffff0000u); }

// segmented butterfly: reduces a[HALF*2] over lanes, halving regs per stage
#define BSTAGE(MASK, HALF)                                        \
  { const bool hi_ = (lane & (MASK)) != 0;                        \
    _Pragma("unroll")                                             \
    for (int k_ = 0; k_ < (HALF); ++k_) {                         \
      float mine_ = hi_ ? a[k_ + (HALF)] : a[k_];                 \
      float oth_  = hi_ ? a[k_] : a[k_ + (HALF)];                 \
      a[k_] = mine_ + __shfl_xor(oth_, (MASK));                   \
    } }

// ---------------------------------------------------------------- k0: fold weights
__global__ __launch_bounds__(256) void k0_pre(const float* __restrict__ W_lin,
                                              const float* __restrict__ b_lin,
                                              const float* __restrict__ W_att,
                                              const float* __restrict__ Wa,
                                              const float* __restrict__ Wb,
                                              const float* __restrict__ Wn,
                                              const float* __restrict__ Wl,
                                              float* __restrict__ pre) {
  int t = threadIdx.x;
  for (int i = t; i < 1024; i += 256) {
    int o = i >> 6, d = i & 63;
    float sa = 0.f, sb = 0.f;
    for (int c = 0; c < 32; ++c) {
      float wl = W_lin[c * 64 + d];
      sa += Wa[o * 32 + c] * wl;
      sb += Wb[o * 32 + c] * wl;
    }
    pre[P_WAL + i] = sa;
    pre[P_WBL + i] = sb;
  }
  if (t < 64) {
    float s = 0.f;
    for (int c = 0; c < 32; ++c) s += W_att[c] * W_lin[c * 64 + t];
    pre[P_WEFF + t] = s;
  }
  if (t < 16) {
    float sa = 0.f, sb = 0.f;
    for (int c = 0; c < 32; ++c) {
      sa += Wa[t * 32 + c] * b_lin[c];
      sb += Wb[t * 32 + c] * b_lin[c];
    }
    pre[P_BWA + t] = sa;
    pre[P_BWB + t] = sb;
  }
  if (t == 0) {
    float s = 0.f;
    for (int c = 0; c < 32; ++c) s += W_att[c] * b_lin[c];
    pre[P_C0] = s;
  }
  __syncthreads();
  for (int i = t; i < 1024; i += 256) {
    int p_ = i >> 6, d = i & 63;
    float sl = 0.f, sn = 0.f;
    for (int o = 0; o < 16; ++o) {
      sl += Wl[p_ * 16 + o] * pre[P_WBL + o * 64 + d];
      sn += Wn[p_ * 16 + o] * pre[P_WAL + o * 64 + d];
    }
    pre[P_WLBL + i] = sl;
    pre[P_WNAL + i] = sn;
  }
  if (t < 16) {
    float sl = 0.f, sn = 0.f;
    for (int o = 0; o < 16; ++o) {
      sl += Wl[t * 16 + o] * pre[P_BWB + o];
      sn += Wn[t * 16 + o] * pre[P_BWA + o];
    }
    pre[P_BWL + t] = sl;
    pre[P_BWN + t] = sn;
  }
}

// ---------------------------------------------------------------- k1: fused per-batch module (3 blocks/CU, no spills)
__global__ __launch_bounds__(512, 3) void k1_fused(
    const float* __restrict__ xl_all, const float* __restrict__ xg_all,
    const float* __restrict__ pre, const float* __restrict__ Wc_g,
    const float* __restrict__ Wd_g, float* __restrict__ out,
    float* __restrict__ bn_part) {
  // union region: scratch5 (10240 B, dead after seg A) overlaid by slabI/slabV (16384 B)
  __shared__ __align__(16) char RU[16384];
  float (*scratch5)[8][64] = (float(*)[8][64])RU;          // [5][8][64]
  f32x4 (*slabI)[4] = (f32x4(*)[4])RU;                     // [128][4]
  f32x4 (*slabV)[4] = (f32x4(*)[4])(RU + 8192);            // [128][4]
  __shared__ unsigned short xaggi[128 * 70];               // bf16 (17920 B)
  __shared__ float pe[40];
  __shared__ float xagg_inter[320];
  __shared__ float s_small[160];
  __shared__ float s_Wd[32][34];
  __shared__ float part1[8][32];
  __shared__ float part2[8][32];

  const int t = threadIdx.x;
  const int b = blockIdx.x;
  const int lane = t & 63;
  const int w = t >> 6;                 // 8 waves
  const int q = lane >> 4;
  const int i16 = lane & 15;
  const int n2 = t >> 2;                // phase 3/4: n index
  const int q3 = t & 3;                 // phase 3/4: i-quarter / o-quarter

  const float* xl = xl_all + (size_t)b * (5 * 128 * 64);
  const f32x4 weff4 = ((const f32x4*)(pre + P_WEFF))[i16];
  const float c0 = pre[P_C0];

  // stage Wd into LDS (read in phase 4; bar1..bar3 order it)
  for (int i = t; i < 1024; i += 512) s_Wd[i >> 5][i & 31] = Wd_g[i];

  // ---------------- phase 1: streaming softmax aggregation over x_local
  const float* xb = xl + (size_t)(16 * w + q) * 64 + 4 * i16;
  f32x4 acc[4];
  float Zk[4];
  #pragma unroll
  for (int k = 0; k < 4; ++k) { acc[k] = (f32x4)0.f; Zk[k] = 0.f; }

  #pragma unroll
  for (int m = 0; m < 5; ++m) {
    f32x4 xc[4];
    const float* xp = xb + (size_t)m * 8192;
    #pragma unroll
    for (int k = 0; k < 4; ++k) xc[k] = *(const f32x4*)(xp + k * 256);
    float a0, a1, a2, a3;
    {
      f32x4 p0 = xc[0] * weff4, p1 = xc[1] * weff4, p2 = xc[2] * weff4, p3 = xc[3] * weff4;
      a0 = p0.x + p0.y + p0.z + p0.w;
      a1 = p1.x + p1.y + p1.z + p1.w;
      a2 = p2.x + p2.y + p2.z + p2.w;
      a3 = p3.x + p3.y + p3.z + p3.w;
    }
    #pragma unroll
    for (int mask = 1; mask <= 8; mask <<= 1) {
      a0 += __shfl_xor(a0, mask);
      a1 += __shfl_xor(a1, mask);
      a2 += __shfl_xor(a2, mask);
      a3 += __shfl_xor(a3, mask);
    }
    float e0 = __expf(a0 + c0), e1 = __expf(a1 + c0);
    float e2 = __expf(a2 + c0), e3 = __expf(a3 + c0);
    Zk[0] += e0; Zk[1] += e1; Zk[2] += e2; Zk[3] += e3;
    f32x4 pim;
    {
      f32x4 pr0 = e0 * xc[0];
      f32x4 pr1 = e1 * xc[1];
      f32x4 pr2 = e2 * xc[2];
      f32x4 pr3 = e3 * xc[3];
      acc[0] += pr0; acc[1] += pr1; acc[2] += pr2; acc[3] += pr3;
      pim = pr0 + pr1 + pr2 + pr3;
    }
    float se = e0 + e1 + e2 + e3;
    #pragma unroll
    for (int mask = 16; mask <= 32; mask <<= 1) {
      pim.x += __shfl_xor(pim.x, mask);
      pim.y += __shfl_xor(pim.y, mask);
      pim.z += __shfl_xor(pim.z, mask);
      pim.w += __shfl_xor(pim.w, mask);
      se += __shfl_xor(se, mask);
    }
    if (lane < 16) {
      *(f32x4*)&scratch5[m][w][i16 * 4] = pim;
      if (i16 == 0) pe[m * 8 + w] = se;
    }
  }
  // normalize intra rows (thread-local) -> bf16 LDS
  #pragma unroll
  for (int k = 0; k < 4; ++k) {
    float invz = 1.f / Zk[k];
    f32x4 v = acc[k] * invz;
    int r = 16 * w + 4 * k + q;
    *(unsigned int*)&xaggi[r * 70 + 4 * i16]     = pack2bf(v.x, v.y);
    *(unsigned int*)&xaggi[r * 70 + 4 * i16 + 2] = pack2bf(v.z, v.w);
  }
  __syncthreads();  // bar1

  // ---------------- seg A: inter-combine (last scratch5 readers) + xg load + xlog
  if (t < 320) {
    int mm = t >> 6, d = t & 63;
    float s = 0.f;
    #pragma unroll
    for (int j = 0; j < 8; ++j) s += scratch5[mm][j][d];
    float sume = pe[mm * 8 + 0] + pe[mm * 8 + 1] + pe[mm * 8 + 2] + pe[mm * 8 + 3] +
                 pe[mm * 8 + 4] + pe[mm * 8 + 5] + pe[mm * 8 + 6] + pe[mm * 8 + 7];
    xagg_inter[mm * 64 + d] = s / sume;
  }
  f32x2 xl2[8];
  {
    f32x2 xv[16];
    const f32x2* xgr = (const f32x2*)(xg_all + ((size_t)b * 128 + n2) * 32);
    #pragma unroll
    for (int j = 0; j < 16; ++j) xv[j] = xgr[j];
    #pragma unroll
    for (int o2 = 0; o2 < 8; ++o2) {
      f32x2 r;
      #pragma unroll
      for (int jj = 0; jj < 2; ++jj) {
        const int o = o2 * 2 + jj;
        f32x2 s = (f32x2)0.f;
        #pragma unroll
        for (int j = 0; j < 16; ++j) s += xv[j] * *(const f32x2*)(Wc_g + o * 32 + 2 * j);
        r[jj] = s.x + s.y;
      }
      xl2[o2] = r;
    }
  }
  __syncthreads();  // bar2 (scratch5 dead; slabs may now overwrite)

  // ---------------- seg B: per-s projections into slabs + tiny inter projections
  {
    const int q2 = __builtin_amdgcn_readfirstlane(t >> 7);   // 0..3 wave-uniform
    const int s2 = t & 127;
    const float* Wbase = pre + ((q2 < 2) ? P_WBL : P_WLBL) + (q2 & 1) * 512;
    const unsigned short* xrow = &xaggi[s2 * 70];
    f32x2 a2[8];
    #pragma unroll
    for (int r = 0; r < 8; ++r) a2[r] = (f32x2)0.f;
    #pragma unroll
    for (int c2 = 0; c2 < 32; ++c2) {
      unsigned int u = *(const unsigned int*)(xrow + 2 * c2);
      f32x2 xa;
      xa.x = bflo(u);
      xa.y = bfhi(u);
      #pragma unroll
      for (int r = 0; r < 8; ++r)
        a2[r] += xa * *(const f32x2*)(Wbase + r * 64 + 2 * c2);
    }
    const int bb = ((q2 < 2) ? P_BWB : P_BWL) + (q2 & 1) * 8;
    f32x4* dst = ((q2 < 2) ? &slabI[s2][0] : &slabV[s2][0]) + (q2 & 1) * 2;
    f32x4 o0, o1;
    o0.x = a2[0].x + a2[0].y + pre[bb + 0];
    o0.y = a2[1].x + a2[1].y + pre[bb + 1];
    o0.z = a2[2].x + a2[2].y + pre[bb + 2];
    o0.w = a2[3].x + a2[3].y + pre[bb + 3];
    o1.x = a2[4].x + a2[4].y + pre[bb + 4];
    o1.y = a2[5].x + a2[5].y + pre[bb + 5];
    o1.z = a2[6].x + a2[6].y + pre[bb + 6];
    o1.w = a2[7].x + a2[7].y + pre[bb + 7];
    dst[0] = o0;
    dst[1] = o1;
  }
  if (t < 160) {
    int o2 = t & 31, mm = t >> 5;
    const float* wr = pre + ((o2 < 16) ? (P_WAL + o2 * 64) : (P_WNAL + (o2 - 16) * 64));
    float p = 0.f;
    #pragma unroll
    for (int d = 0; d < 64; ++d) p += wr[d] * xagg_inter[mm * 64 + d];
    p += (o2 < 16) ? pre[P_BWA + o2] : pre[P_BWN + (o2 - 16)];
    if (o2 < 16) s_small[mm * 16 + o2] = p;
    else s_small[80 + mm * 16 + (o2 - 16)] = p;
  }
  __syncthreads();  // bar3

  // ---------------- phase 3: f_intra partial sums, i = q3 + 4k
  float sum = 0.f;
  f32x4 fav[4];
  #pragma unroll
  for (int c = 0; c < 4; ++c) fav[c] = (f32x4)0.f;
  for (int k = 0; k < 32; ++k) {
    const int i = q3 + 4 * k;
    f32x2 d2 = (f32x2)0.f;
    #pragma unroll
    for (int c = 0; c < 4; ++c) {
      f32x4 ch = slabI[i][c];
      f32x2 lo; lo.x = ch.x; lo.y = ch.y;
      f32x2 hi; hi.x = ch.z; hi.y = ch.w;
      d2 += xl2[2 * c] * lo;
      d2 += xl2[2 * c + 1] * hi;
    }
    float e = __expf(d2.x + d2.y);
    sum += e;
    #pragma unroll
    for (int c = 0; c < 4; ++c) fav[c] += e * slabV[i][c];
  }
  sum += __shfl_xor(sum, 1);
  sum += __shfl_xor(sum, 2);
  #pragma unroll
  for (int c = 0; c < 4; ++c) {
    fav[c].x += __shfl_xor(fav[c].x, 1);
    fav[c].y += __shfl_xor(fav[c].y, 1);
    fav[c].z += __shfl_xor(fav[c].z, 1);
    fav[c].w += __shfl_xor(fav[c].w, 1);
    fav[c].x += __shfl_xor(fav[c].x, 2);
    fav[c].y += __shfl_xor(fav[c].y, 2);
    fav[c].z += __shfl_xor(fav[c].z, 2);
    fav[c].w += __shfl_xor(fav[c].w, 2);
  }
  const float inv = 1.f / sum;
  f32x2 fin2[8];
  #pragma unroll
  for (int j = 0; j < 8; ++j) {
    fin2[j].x = fav[j >> 1][2 * (j & 1)] * inv;
    fin2[j].y = fav[j >> 1][2 * (j & 1) + 1] * inv;
  }

  // ---------------- phase 4: f_inter, feat (o-quarter per lane), BN partials
  float L[5], mx3 = -1e30f;
  #pragma unroll
  for (int mm = 0; mm < 5; ++mm) {
    float p = 0.f;
    #pragma unroll
    for (int j = 0; j < 8; ++j) {
      p += xl2[j].x * s_small[mm * 16 + 2 * j];
      p += xl2[j].y * s_small[mm * 16 + 2 * j + 1];
    }
    L[mm] = p;
    mx3 = fmaxf(mx3, p);
  }
  float sum3 = 0.f;
  #pragma unroll
  for (int mm = 0; mm < 5; ++mm) { L[mm] = __expf(L[mm] - mx3); sum3 += L[mm]; }
  const float inv3 = 1.f / sum3;
  f32x2 fi2[8];
  #pragma unroll
  for (int j = 0; j < 8; ++j) {
    f32x2 r = (f32x2)0.f;
    #pragma unroll
    for (int mm = 0; mm < 5; ++mm) {
      r.x += L[mm] * s_small[80 + mm * 16 + 2 * j];
      r.y += L[mm] * s_small[80 + mm * 16 + 2 * j + 1];
    }
    fi2[j].x = r.x * inv3;
    fi2[j].y = r.y * inv3;
  }
  float fo[8];
  #pragma unroll
  for (int j = 0; j < 8; ++j) {
    const int o = 8 * q3 + j;
    const f32x2* wd = (const f32x2*)&s_Wd[o][0];
    f32x2 s = fi2[0] * wd[0];
    #pragma unroll
    for (int jj = 1; jj < 8; ++jj) s += fi2[jj] * wd[jj];
    #pragma unroll
    for (int jj = 0; jj < 8; ++jj) s += fin2[jj] * wd[8 + jj];
    fo[j] = s.x + s.y;
  }
  {
    float* op = out + ((size_t)b * 128 + n2) * 32 + 8 * q3;
    ((f32x4*)op)[0] = *(f32x4*)&fo[0];
    ((f32x4*)op)[1] = *(f32x4*)&fo[4];
  }
  const int omap = 8 * q3 + 4 * ((lane >> 2) & 1) + 2 * ((lane >> 3) & 1) + ((lane >> 4) & 1);
  {
    float a[8];
    #pragma unroll
    for (int j = 0; j < 8; ++j) a[j] = fo[j];
    BSTAGE(4, 4) BSTAGE(8, 2) BSTAGE(16, 1)
    a[0] += __shfl_xor(a[0], 32);
    if (lane < 32) part1[w][omap] = a[0];
  }
  {
    float a[8];
    #pragma unroll
    for (int j = 0; j < 8; ++j) a[j] = fo[j] * fo[j];
    BSTAGE(4, 4) BSTAGE(8, 2) BSTAGE(16, 1)
    a[0] += __shfl_xor(a[0], 32);
    if (lane < 32) part2[w][omap] = a[0];
  }
  __syncthreads();  // bar4
  if (t < 64) {
    int c = t & 31, h = t >> 5;
    float v = 0.f;
    #pragma unroll
    for (int j = 0; j < 8; ++j) v += h ? part2[j][c] : part1[j][c];
    bn_part[(size_t)b * 64 + h * 32 + c] = v;
  }
}

// ---------------------------------------------------------------- k2: BN coefficients (one block per channel)
__global__ __launch_bounds__(256, 1) void k2_stats(const float* __restrict__ bn_part,
                                                   const float* __restrict__ gamma,
                                                   const float* __restrict__ beta,
                                                   float* __restrict__ coef) {
  __shared__ float red[2][4];
  const int c = blockIdx.x;              // 0..31
  const int t = threadIdx.x;
  const int lane = t & 63, w = t >> 6;
  float s1 = 0.f, s2 = 0.f;
  for (int bb = t; bb < NB; bb += 256) {
    s1 += bn_part[(size_t)bb * 64 + c];
    s2 += bn_part[(size_t)bb * 64 + c + 32];
  }
  #pragma unroll
  for (int mask = 1; mask <= 32; mask <<= 1) {
    s1 += __shfl_xor(s1, mask);
    s2 += __shfl_xor(s2, mask);
  }
  if (lane == 0) { red[0][w] = s1; red[1][w] = s2; }
  __syncthreads();
  if (t == 0) {
    float S1 = red[0][0] + red[0][1] + red[0][2] + red[0][3];
    float S2 = red[1][0] + red[1][1] + red[1][2] + red[1][3];
    const float inv = 1.f / (float)(NB * 128);
    float mean = S1 * inv;
    float var = S2 * inv - mean * mean;
    float scl = gamma[c] * rsqrtf(var + 1e-5f);
    coef[c] = scl;
    coef[32 + c] = beta[c] - mean * scl;
  }
}

// ---------------------------------------------------------------- k3: BN apply + residual + leaky (in place)
__global__ __launch_bounds__(256) void k3_final(const float* __restrict__ xg,
                                                float* __restrict__ out,
                                                const float* __restrict__ coef) {
  __shared__ float s_c[64];
  if (threadIdx.x < 64) s_c[threadIdx.x] = coef[threadIdx.x];
  __syncthreads();
  size_t i4 = (size_t)blockIdx.x * 256 + threadIdx.x;
  float4 f = ((const float4*)out)[i4];
  float4 x = ((const float4*)xg)[i4];
  int c = (int)((i4 * 4) & 31);
  float4 r;
  r.x = x.x + f.x * s_c[c + 0] + s_c[32 + c + 0];
  r.y = x.y + f.y * s_c[c + 1] + s_c[32 + c + 1];
  r.z = x.z + f.z * s_c[c + 2] + s_c[32 + c + 2];
  r.w = x.w + f.w * s_c[c + 3] + s_c[32 + c + 3];
  r.x = r.x >= 0.f ? r.x : 0.2f * r.x;
  r.y = r.y >= 0.f ? r.y : 0.2f * r.y;
  r.z = r.z >= 0.f ? r.z : 0.2f * r.z;
  r.w = r.w >= 0.f ? r.w : 0.2f * r.w;
  ((float4*)out)[i4] = r;
}

// ----------------------------------------------------------------
extern "C" void kernel_launch(void* const* d_in, const int* in_sizes, int n_in,
                              void* d_out, int out_size, void* d_ws, size_t ws_size,
                              hipStream_t stream) {
  const float* xg    = (const float*)d_in[0];
  const float* xl    = (const float*)d_in[1];
  const float* W_lin = (const float*)d_in[2];
  const float* b_lin = (const float*)d_in[3];
  const float* W_att = (const float*)d_in[4];
  const float* Wa    = (const float*)d_in[5];
  const float* Wb    = (const float*)d_in[6];
  const float* Wc    = (const float*)d_in[7];
  const float* Wn    = (const float*)d_in[8];
  const float* Wl    = (const float*)d_in[9];
  const float* Wd    = (const float*)d_in[10];
  const float* gamma = (const float*)d_in[11];
  const float* beta  = (const float*)d_in[12];
  float* out = (float*)d_out;
  float* ws = (float*)d_ws;
  float* pre = ws;
  float* bn_part = ws + WS_BNPART;
  float* coef = ws + WS_COEF;

  hipLaunchKernelGGL(k0_pre, dim3(1), dim3(256), 0, stream,
                     W_lin, b_lin, W_att, Wa, Wb, Wn, Wl, pre);
  hipLaunchKernelGGL(k1_fused, dim3(NB), dim3(512), 0, stream,
                     xl, xg, pre, Wc, Wd, out, bn_part);
  hipLaunchKernelGGL(k2_stats, dim3(32), dim3(256), 0, stream, bn_part, gamma, beta, coef);
  hipLaunchKernelGGL(k3_final, dim3(8192), dim3(256), 0, stream, xg, out, coef);
}

// Round 8
// 275.965 us; speedup vs baseline: 1.2161x; 1.2161x over previous
//
#include <hip/hip_runtime.h>
#include <math.h>

#define NB 2048
typedef float f32x4 __attribute__((ext_vector_type(4)));
typedef float f32x2 __attribute__((ext_vector_type(2)));

// pre[] float offsets (folded weights)
#define P_WAL 0
#define P_WBL 1024
#define P_WLBL 2048
#define P_WNAL 3072
#define P_WEFF 4096
#define P_BWA 4160
#define P_BWB 4176
#define P_BWL 4192
#define P_BWN 4208
#define P_C0  4224

// ws float offsets
#define WS_BNPART 4352
#define WS_COEF   135424
#define WS_SMALL  135488                  // [2048][160]
#define WS_BIG_I  463168                  // [2048][2048] f32: intra2T rows [s][16]
#define WS_BIG_V  (463168 + 4194304)      // [2048][2048] f32: v_intra rows [s][16]

__device__ __forceinline__ unsigned short f2bf(float f) {
  unsigned int u = __float_as_uint(f);
  u += 0x7fffu + ((u >> 16) & 1u);
  return (unsigned short)(u >> 16);
}
__device__ __forceinline__ unsigned int pack2bf(float lo, float hi) {
  return (unsigned int)f2bf(lo) | ((unsigned int)f2bf(hi) << 16);
}
__device__ __forceinline__ float bflo(unsigned int u) { return __uint_as_float(u << 16); }
__device__ __forceinline__ float bfhi(unsigned int u) { return __uint_as_float(u & 0xffff0000u); }

// segmented butterfly: reduces a[HALF*2] over lanes, halving regs per stage
#define BSTAGE(MASK, HALF)                                        \
  { const bool hi_ = (lane & (MASK)) != 0;                        \
    _Pragma("unroll")                                             \
    for (int k_ = 0; k_ < (HALF); ++k_) {                         \
      float mine_ = hi_ ? a[k_ + (HALF)] : a[k_];                 \
      float oth_  = hi_ ? a[k_] : a[k_ + (HALF)];                 \
      a[k_] = mine_ + __shfl_xor(oth_, (MASK));                   \
    } }

// ---------------------------------------------------------------- k0: fold weights
__global__ __launch_bounds__(256) void k0_pre(const float* __restrict__ W_lin,
                                              const float* __restrict__ b_lin,
                                              const float* __restrict__ W_att,
                                              const float* __restrict__ Wa,
                                              const float* __restrict__ Wb,
                                              const float* __restrict__ Wn,
                                              const float* __restrict__ Wl,
                                              float* __restrict__ pre) {
  int t = threadIdx.x;
  for (int i = t; i < 1024; i += 256) {
    int o = i >> 6, d = i & 63;
    float sa = 0.f, sb = 0.f;
    for (int c = 0; c < 32; ++c) {
      float wl = W_lin[c * 64 + d];
      sa += Wa[o * 32 + c] * wl;
      sb += Wb[o * 32 + c] * wl;
    }
    pre[P_WAL + i] = sa;
    pre[P_WBL + i] = sb;
  }
  if (t < 64) {
    float s = 0.f;
    for (int c = 0; c < 32; ++c) s += W_att[c] * W_lin[c * 64 + t];
    pre[P_WEFF + t] = s;
  }
  if (t < 16) {
    float sa = 0.f, sb = 0.f;
    for (int c = 0; c < 32; ++c) {
      sa += Wa[t * 32 + c] * b_lin[c];
      sb += Wb[t * 32 + c] * b_lin[c];
    }
    pre[P_BWA + t] = sa;
    pre[P_BWB + t] = sb;
  }
  if (t == 0) {
    float s = 0.f;
    for (int c = 0; c < 32; ++c) s += W_att[c] * b_lin[c];
    pre[P_C0] = s;
  }
  __syncthreads();
  for (int i = t; i < 1024; i += 256) {
    int p_ = i >> 6, d = i & 63;
    float sl = 0.f, sn = 0.f;
    for (int o = 0; o < 16; ++o) {
      sl += Wl[p_ * 16 + o] * pre[P_WBL + o * 64 + d];
      sn += Wn[p_ * 16 + o] * pre[P_WAL + o * 64 + d];
    }
    pre[P_WLBL + i] = sl;
    pre[P_WNAL + i] = sn;
  }
  if (t < 16) {
    float sl = 0.f, sn = 0.f;
    for (int o = 0; o < 16; ++o) {
      sl += Wl[t * 16 + o] * pre[P_BWB + o];
      sn += Wn[t * 16 + o] * pre[P_BWA + o];
    }
    pre[P_BWL + t] = sl;
    pre[P_BWN + t] = sn;
  }
}

// ---------------------------------------------------------------- k1a: streaming aggregation + projections (R4 structure, bf16 xaggi)
__global__ __launch_bounds__(512, 1) void k1a(
    const float* __restrict__ xl_all, const float* __restrict__ pre,
    float* __restrict__ p_small, float* __restrict__ bigI,
    float* __restrict__ bigV) {
  __shared__ unsigned short xaggi[128 * 70];        // bf16 (17920 B)
  __shared__ f32x4 scratch5[5][8][16];              // per-m, per-wave inter partials
  __shared__ float pe[5][8];
  __shared__ float xagg_inter[5][64];

  const int t = threadIdx.x;
  const int b = blockIdx.x;
  const int lane = t & 63;
  const int w = t >> 6;                 // 8 waves; wave owns rows 16w..16w+15
  const int q = lane >> 4;              // row offset within group of 4
  const int i16 = lane & 15;            // d-chunk (4 floats)

  const float* xl = xl_all + (size_t)b * (5 * 128 * 64);
  const f32x4 weff4 = ((const f32x4*)(pre + P_WEFF))[i16];
  const float c0 = pre[P_C0];

  // row(k) = 16w + 4k + q; float offset = row*64 + 4*i16
  const float* xb = xl + (size_t)(16 * w + q) * 64 + 4 * i16;

  f32x4 xA[4], xB[4], acc[4];
  float Zk[4];
  #pragma unroll
  for (int k = 0; k < 4; ++k) {
    acc[k] = (f32x4)0.f;
    Zk[k] = 0.f;
    xA[k] = *(const f32x4*)(xb + k * 256);
  }

  #pragma unroll
  for (int m = 0; m < 5; ++m) {
    f32x4* xc = (m & 1) ? xB : xA;
    f32x4* xn = (m & 1) ? xA : xB;
    if (m < 4) {
      const float* np = xb + (size_t)(m + 1) * 8192;
      #pragma unroll
      for (int k = 0; k < 4; ++k) xn[k] = *(const f32x4*)(np + k * 256);
    }
    // row dots: partial dot4 then butterfly over the 16-lane group
    float a0, a1, a2, a3;
    {
      f32x4 p0 = xc[0] * weff4, p1 = xc[1] * weff4, p2 = xc[2] * weff4, p3 = xc[3] * weff4;
      a0 = p0.x + p0.y + p0.z + p0.w;
      a1 = p1.x + p1.y + p1.z + p1.w;
      a2 = p2.x + p2.y + p2.z + p2.w;
      a3 = p3.x + p3.y + p3.z + p3.w;
    }
    #pragma unroll
    for (int mask = 1; mask <= 8; mask <<= 1) {
      a0 += __shfl_xor(a0, mask);
      a1 += __shfl_xor(a1, mask);
      a2 += __shfl_xor(a2, mask);
      a3 += __shfl_xor(a3, mask);
    }
    float e0 = __expf(a0 + c0), e1 = __expf(a1 + c0);
    float e2 = __expf(a2 + c0), e3 = __expf(a3 + c0);
    Zk[0] += e0; Zk[1] += e1; Zk[2] += e2; Zk[3] += e3;
    f32x4 pim;
    {
      f32x4 pr0 = e0 * xc[0];
      f32x4 pr1 = e1 * xc[1];
      f32x4 pr2 = e2 * xc[2];
      f32x4 pr3 = e3 * xc[3];
      acc[0] += pr0; acc[1] += pr1; acc[2] += pr2; acc[3] += pr3;
      pim = pr0 + pr1 + pr2 + pr3;
    }
    float se = e0 + e1 + e2 + e3;
    #pragma unroll
    for (int mask = 16; mask <= 32; mask <<= 1) {
      pim.x += __shfl_xor(pim.x, mask);
      pim.y += __shfl_xor(pim.y, mask);
      pim.z += __shfl_xor(pim.z, mask);
      pim.w += __shfl_xor(pim.w, mask);
      se += __shfl_xor(se, mask);
    }
    if (lane < 16) {
      scratch5[m][w][i16] = pim;
      if (i16 == 0) pe[m][w] = se;
    }
  }

  // normalize intra rows (thread-local) -> bf16 LDS
  #pragma unroll
  for (int k = 0; k < 4; ++k) {
    float invz = 1.f / Zk[k];
    f32x4 v = acc[k] * invz;
    int r = 16 * w + 4 * k + q;
    *(unsigned int*)&xaggi[r * 70 + 4 * i16]     = pack2bf(v.x, v.y);
    *(unsigned int*)&xaggi[r * 70 + 4 * i16 + 2] = pack2bf(v.z, v.w);
  }
  __syncthreads();

  // combine inter aggregates across waves, normalize
  if (t < 320) {
    int mm = t >> 6, d = t & 63;
    const float* sp = (const float*)&scratch5[mm][0][0];
    float s = 0.f;
    #pragma unroll
    for (int j = 0; j < 8; ++j) s += sp[j * 64 + d];
    float sume = pe[mm][0] + pe[mm][1] + pe[mm][2] + pe[mm][3] +
                 pe[mm][4] + pe[mm][5] + pe[mm][6] + pe[mm][7];
    xagg_inter[mm][d] = s / sume;
  }
  __syncthreads();

  // phase 2a: per-s projections (intra2 -> bigI, v_intra -> bigV)
  {
    const int q2 = __builtin_amdgcn_readfirstlane(t >> 7);   // 0..3, wave-uniform
    const int s2 = t & 127;
    const float* Wbase = pre + ((q2 < 2) ? P_WBL : P_WLBL) + (q2 & 1) * 512;
    const unsigned short* xrow = &xaggi[s2 * 70];
    f32x2 a2[8];
    #pragma unroll
    for (int r = 0; r < 8; ++r) a2[r] = (f32x2)0.f;
    #pragma unroll
    for (int c2 = 0; c2 < 32; ++c2) {
      unsigned int u = *(const unsigned int*)(xrow + 2 * c2);
      f32x2 xa;
      xa.x = bflo(u);
      xa.y = bfhi(u);
      #pragma unroll
      for (int r = 0; r < 8; ++r)
        a2[r] += xa * *(const f32x2*)(Wbase + r * 64 + 2 * c2);
    }
    const int bb = ((q2 < 2) ? P_BWB : P_BWL) + (q2 & 1) * 8;
    float* dst = ((q2 < 2) ? bigI : bigV) + (size_t)b * 2048 + s2 * 16 + (q2 & 1) * 8;
    f32x4 o0, o1;
    o0.x = a2[0].x + a2[0].y + pre[bb + 0];
    o0.y = a2[1].x + a2[1].y + pre[bb + 1];
    o0.z = a2[2].x + a2[2].y + pre[bb + 2];
    o0.w = a2[3].x + a2[3].y + pre[bb + 3];
    o1.x = a2[4].x + a2[4].y + pre[bb + 4];
    o1.y = a2[5].x + a2[5].y + pre[bb + 5];
    o1.z = a2[6].x + a2[6].y + pre[bb + 6];
    o1.w = a2[7].x + a2[7].y + pre[bb + 7];
    *(f32x4*)dst = o0;
    *(f32x4*)(dst + 4) = o1;
  }

  // tiny inter projections: inter2[5][16], v_inter[5][16]
  if (t < 160) {
    int o2 = t & 31, mm = t >> 5;
    const float* wr = pre + ((o2 < 16) ? (P_WAL + o2 * 64) : (P_WNAL + (o2 - 16) * 64));
    float p = 0.f;
    #pragma unroll
    for (int d = 0; d < 64; ++d) p += wr[d] * xagg_inter[mm][d];
    p += (o2 < 16) ? pre[P_BWA + o2] : pre[P_BWN + (o2 - 16)];
    float* os = p_small + (size_t)b * 160;
    if (o2 < 16) os[mm * 16 + o2] = p;
    else os[80 + mm * 16 + (o2 - 16)] = p;
  }
}

// ---------------------------------------------------------------- k1b: attention + feat + BN partials (4 threads per n)
__global__ __launch_bounds__(512, 1) void k1b(
    const float* __restrict__ xg_all, const float* __restrict__ Wc_g,
    const float* __restrict__ Wd_g, const float* __restrict__ p_small,
    const float* __restrict__ bigI, const float* __restrict__ bigV,
    float* __restrict__ out, float* __restrict__ bn_part) {
  __shared__ f32x4 slabI[128][4];
  __shared__ f32x4 slabV[128][4];
  __shared__ float part1[8][32];
  __shared__ float part2[8][32];

  const int t = threadIdx.x;
  const int b = blockIdx.x;
  const int lane = t & 63;
  const int w = t >> 6;
  const int n2 = t >> 2;                // n index
  const int q3 = t & 3;                 // i-quarter / o-quarter

  // stage I/V slabs (16 KB, coalesced: 512 threads x 2 f32x4 each)
  const f32x4* gI = (const f32x4*)(bigI + (size_t)b * 2048);
  const f32x4* gV = (const f32x4*)(bigV + (size_t)b * 2048);
  ((f32x4*)slabI)[t] = gI[t];
  ((f32x4*)slabV)[t] = gV[t];

  // xlog for n2 (4 q-partner threads compute identical copies)
  f32x2 xl2[8];
  {
    f32x2 xv[16];
    const f32x2* xgr = (const f32x2*)(xg_all + ((size_t)b * 128 + n2) * 32);
    #pragma unroll
    for (int j = 0; j < 16; ++j) xv[j] = xgr[j];
    #pragma unroll
    for (int o2 = 0; o2 < 8; ++o2) {
      f32x2 r;
      #pragma unroll
      for (int jj = 0; jj < 2; ++jj) {
        const int o = o2 * 2 + jj;
        f32x2 s = (f32x2)0.f;
        #pragma unroll
        for (int j = 0; j < 16; ++j) s += xv[j] * *(const f32x2*)(Wc_g + o * 32 + 2 * j);
        r[jj] = s.x + s.y;
      }
      xl2[o2] = r;
    }
  }
  __syncthreads();

  // f_intra partial sums over i = q3 + 4k
  float sum = 0.f;
  f32x4 fav[4];
  #pragma unroll
  for (int c = 0; c < 4; ++c) fav[c] = (f32x4)0.f;
  for (int k = 0; k < 32; ++k) {
    const int i = q3 + 4 * k;
    f32x2 d2 = (f32x2)0.f;
    #pragma unroll
    for (int c = 0; c < 4; ++c) {
      f32x4 ch = slabI[i][c];
      f32x2 lo; lo.x = ch.x; lo.y = ch.y;
      f32x2 hi; hi.x = ch.z; hi.y = ch.w;
      d2 += xl2[2 * c] * lo;
      d2 += xl2[2 * c + 1] * hi;
    }
    float e = __expf(d2.x + d2.y);
    sum += e;
    #pragma unroll
    for (int c = 0; c < 4; ++c) fav[c] += e * slabV[i][c];
  }
  // combine the 4 q-partners (adjacent lanes)
  sum += __shfl_xor(sum, 1);
  sum += __shfl_xor(sum, 2);
  #pragma unroll
  for (int c = 0; c < 4; ++c) {
    fav[c].x += __shfl_xor(fav[c].x, 1);
    fav[c].y += __shfl_xor(fav[c].y, 1);
    fav[c].z += __shfl_xor(fav[c].z, 1);
    fav[c].w += __shfl_xor(fav[c].w, 1);
    fav[c].x += __shfl_xor(fav[c].x, 2);
    fav[c].y += __shfl_xor(fav[c].y, 2);
    fav[c].z += __shfl_xor(fav[c].z, 2);
    fav[c].w += __shfl_xor(fav[c].w, 2);
  }
  const float inv = 1.f / sum;
  f32x2 fin2[8];
  #pragma unroll
  for (int j = 0; j < 8; ++j) {
    fin2[j].x = fav[j >> 1][2 * (j & 1)] * inv;
    fin2[j].y = fav[j >> 1][2 * (j & 1) + 1] * inv;
  }

  // f_inter (5-way softmax), duplicated across partners; weights via scalar loads
  const float* sm = p_small + (size_t)b * 160;
  float L[5], mx3 = -1e30f;
  #pragma unroll
  for (int mm = 0; mm < 5; ++mm) {
    float p = 0.f;
    #pragma unroll
    for (int j = 0; j < 8; ++j) {
      p += xl2[j].x * sm[mm * 16 + 2 * j];
      p += xl2[j].y * sm[mm * 16 + 2 * j + 1];
    }
    L[mm] = p;
    mx3 = fmaxf(mx3, p);
  }
  float sum3 = 0.f;
  #pragma unroll
  for (int mm = 0; mm < 5; ++mm) { L[mm] = __expf(L[mm] - mx3); sum3 += L[mm]; }
  const float inv3 = 1.f / sum3;
  f32x2 fi2[8];
  #pragma unroll
  for (int j = 0; j < 8; ++j) {
    f32x2 r = (f32x2)0.f;
    #pragma unroll
    for (int mm = 0; mm < 5; ++mm) {
      r.x += L[mm] * sm[80 + mm * 16 + 2 * j];
      r.y += L[mm] * sm[80 + mm * 16 + 2 * j + 1];
    }
    fi2[j].x = r.x * inv3;
    fi2[j].y = r.y * inv3;
  }

  // feat for o in [8*q3, 8*q3+8)
  float fo[8];
  #pragma unroll
  for (int j = 0; j < 8; ++j) {
    const int o = 8 * q3 + j;
    const f32x2* wd = (const f32x2*)(Wd_g + o * 32);
    f32x2 s = fi2[0] * wd[0];
    #pragma unroll
    for (int jj = 1; jj < 8; ++jj) s += fi2[jj] * wd[jj];
    #pragma unroll
    for (int jj = 0; jj < 8; ++jj) s += fin2[jj] * wd[8 + jj];
    fo[j] = s.x + s.y;
  }
  {
    float* op = out + ((size_t)b * 128 + n2) * 32 + 8 * q3;
    ((f32x4*)op)[0] = *(f32x4*)&fo[0];
    ((f32x4*)op)[1] = *(f32x4*)&fo[4];
  }
  // BN partials: reduce over the 16 same-q lanes (masks 4,8,16,32)
  const int omap = 8 * q3 + 4 * ((lane >> 2) & 1) + 2 * ((lane >> 3) & 1) + ((lane >> 4) & 1);
  {
    float a[8];
    #pragma unroll
    for (int j = 0; j < 8; ++j) a[j] = fo[j];
    BSTAGE(4, 4) BSTAGE(8, 2) BSTAGE(16, 1)
    a[0] += __shfl_xor(a[0], 32);
    if (lane < 32) part1[w][omap] = a[0];
  }
  {
    float a[8];
    #pragma unroll
    for (int j = 0; j < 8; ++j) a[j] = fo[j] * fo[j];
    BSTAGE(4, 4) BSTAGE(8, 2) BSTAGE(16, 1)
    a[0] += __shfl_xor(a[0], 32);
    if (lane < 32) part2[w][omap] = a[0];
  }
  __syncthreads();
  if (t < 64) {
    int c = t & 31, h = t >> 5;
    float v = 0.f;
    #pragma unroll
    for (int j = 0; j < 8; ++j) v += h ? part2[j][c] : part1[j][c];
    bn_part[(size_t)b * 64 + h * 32 + c] = v;
  }
}

// ---------------------------------------------------------------- k2: BN coefficients (one block per channel)
__global__ __launch_bounds__(256, 1) void k2_stats(const float* __restrict__ bn_part,
                                                   const float* __restrict__ gamma,
                                                   const float* __restrict__ beta,
                                                   float* __restrict__ coef) {
  __shared__ float red[2][4];
  const int c = blockIdx.x;              // 0..31
  const int t = threadIdx.x;
  const int lane = t & 63, w = t >> 6;
  float s1 = 0.f, s2 = 0.f;
  for (int bb = t; bb < NB; bb += 256) {
    s1 += bn_part[(size_t)bb * 64 + c];
    s2 += bn_part[(size_t)bb * 64 + c + 32];
  }
  #pragma unroll
  for (int mask = 1; mask <= 32; mask <<= 1) {
    s1 += __shfl_xor(s1, mask);
    s2 += __shfl_xor(s2, mask);
  }
  if (lane == 0) { red[0][w] = s1; red[1][w] = s2; }
  __syncthreads();
  if (t == 0) {
    float S1 = red[0][0] + red[0][1] + red[0][2] + red[0][3];
    float S2 = red[1][0] + red[1][1] + red[1][2] + red[1][3];
    const float inv = 1.f / (float)(NB * 128);
    float mean = S1 * inv;
    float var = S2 * inv - mean * mean;
    float scl = gamma[c] * rsqrtf(var + 1e-5f);
    coef[c] = scl;
    coef[32 + c] = beta[c] - mean * scl;
  }
}

// ---------------------------------------------------------------- k3: BN apply + residual + leaky (in place)
__global__ __launch_bounds__(256) void k3_final(const float* __restrict__ xg,
                                                float* __restrict__ out,
                                                const float* __restrict__ coef) {
  __shared__ float s_c[64];
  if (threadIdx.x < 64) s_c[threadIdx.x] = coef[threadIdx.x];
  __syncthreads();
  size_t i4 = (size_t)blockIdx.x * 256 + threadIdx.x;
  float4 f = ((const float4*)out)[i4];
  float4 x = ((const float4*)xg)[i4];
  int c = (int)((i4 * 4) & 31);
  float4 r;
  r.x = x.x + f.x * s_c[c + 0] + s_c[32 + c + 0];
  r.y = x.y + f.y * s_c[c + 1] + s_c[32 + c + 1];
  r.z = x.z + f.z * s_c[c + 2] + s_c[32 + c + 2];
  r.w = x.w + f.w * s_c[c + 3] + s_c[32 + c + 3];
  r.x = r.x >= 0.f ? r.x : 0.2f * r.x;
  r.y = r.y >= 0.f ? r.y : 0.2f * r.y;
  r.z = r.z >= 0.f ? r.z : 0.2f * r.z;
  r.w = r.w >= 0.f ? r.w : 0.2f * r.w;
  ((float4*)out)[i4] = r;
}

// ----------------------------------------------------------------
extern "C" void kernel_launch(void* const* d_in, const int* in_sizes, int n_in,
                              void* d_out, int out_size, void* d_ws, size_t ws_size,
                              hipStream_t stream) {
  const float* xg    = (const float*)d_in[0];
  const float* xl    = (const float*)d_in[1];
  const float* W_lin = (const float*)d_in[2];
  const float* b_lin = (const float*)d_in[3];
  const float* W_att = (const float*)d_in[4];
  const float* Wa    = (const float*)d_in[5];
  const float* Wb    = (const float*)d_in[6];
  const float* Wc    = (const float*)d_in[7];
  const float* Wn    = (const float*)d_in[8];
  const float* Wl    = (const float*)d_in[9];
  const float* Wd    = (const float*)d_in[10];
  const float* gamma = (const float*)d_in[11];
  const float* beta  = (const float*)d_in[12];
  float* out = (float*)d_out;
  float* ws = (float*)d_ws;
  float* pre = ws;
  float* bn_part = ws + WS_BNPART;
  float* coef = ws + WS_COEF;
  float* p_small = ws + WS_SMALL;
  float* bigI = ws + WS_BIG_I;
  float* bigV = ws + WS_BIG_V;

  hipLaunchKernelGGL(k0_pre, dim3(1), dim3(256), 0, stream,
                     W_lin, b_lin, W_att, Wa, Wb, Wn, Wl, pre);
  hipLaunchKernelGGL(k1a, dim3(NB), dim3(512), 0, stream, xl, pre, p_small, bigI, bigV);
  hipLaunchKernelGGL(k1b, dim3(NB), dim3(512), 0, stream,
                     xg, Wc, Wd, p_small, bigI, bigV, out, bn_part);
  hipLaunchKernelGGL(k2_stats, dim3(32), dim3(256), 0, stream, bn_part, gamma, beta, coef);
  hipLaunchKernelGGL(k3_final, dim3(8192), dim3(256), 0, stream, xg, out, coef);
}

// Round 9
// 197.512 us; speedup vs baseline: 1.6991x; 1.3972x over previous
//
#include <hip/hip_runtime.h>
#include <math.h>

#define NB 2048
typedef float f32x4 __attribute__((ext_vector_type(4)));
typedef float f32x2 __attribute__((ext_vector_type(2)));

// pre[] float offsets (folded weights)
#define P_WAL 0
#define P_WBL 1024
#define P_WLBL 2048
#define P_WNAL 3072
#define P_WEFF 4096
#define P_BWA 4160
#define P_BWB 4176
#define P_BWL 4192
#define P_BWN 4208
#define P_C0  4224

// ws float offsets
#define WS_BNPART 4352
#define WS_COEF   135424
#define WS_SMALL  135488                  // [2048][160]
#define WS_BIG_I  463168                  // [2048][2048] f32: intra2T rows [s][16]
#define WS_BIG_V  (463168 + 4194304)      // [2048][2048] f32: v_intra rows [s][16]
#define WS_FEAT16 (463168 + 8388608)      // [2048][128][32] bf16 (4194304 floats of storage)

__device__ __forceinline__ unsigned short f2bf(float f) {
  unsigned int u = __float_as_uint(f);
  u += 0x7fffu + ((u >> 16) & 1u);
  return (unsigned short)(u >> 16);
}
__device__ __forceinline__ unsigned int pack2bf(float lo, float hi) {
  return (unsigned int)f2bf(lo) | ((unsigned int)f2bf(hi) << 16);
}
__device__ __forceinline__ float bflo(unsigned int u) { return __uint_as_float(u << 16); }
__device__ __forceinline__ float bfhi(unsigned int u) { return __uint_as_float(u & 0xffff0000u); }

// segmented butterfly: reduces a[HALF*2] over lanes, halving regs per stage
#define BSTAGE(MASK, HALF)                                        \
  { const bool hi_ = (lane & (MASK)) != 0;                        \
    _Pragma("unroll")                                             \
    for (int k_ = 0; k_ < (HALF); ++k_) {                         \
      float mine_ = hi_ ? a[k_ + (HALF)] : a[k_];                 \
      float oth_  = hi_ ? a[k_] : a[k_ + (HALF)];                 \
      a[k_] = mine_ + __shfl_xor(oth_, (MASK));                   \
    } }

// ---------------------------------------------------------------- k0: fold weights
__global__ __launch_bounds__(256) void k0_pre(const float* __restrict__ W_lin,
                                              const float* __restrict__ b_lin,
                                              const float* __restrict__ W_att,
                                              const float* __restrict__ Wa,
                                              const float* __restrict__ Wb,
                                              const float* __restrict__ Wn,
                                              const float* __restrict__ Wl,
                                              float* __restrict__ pre) {
  int t = threadIdx.x;
  for (int i = t; i < 1024; i += 256) {
    int o = i >> 6, d = i & 63;
    float sa = 0.f, sb = 0.f;
    for (int c = 0; c < 32; ++c) {
      float wl = W_lin[c * 64 + d];
      sa += Wa[o * 32 + c] * wl;
      sb += Wb[o * 32 + c] * wl;
    }
    pre[P_WAL + i] = sa;
    pre[P_WBL + i] = sb;
  }
  if (t < 64) {
    float s = 0.f;
    for (int c = 0; c < 32; ++c) s += W_att[c] * W_lin[c * 64 + t];
    pre[P_WEFF + t] = s;
  }
  if (t < 16) {
    float sa = 0.f, sb = 0.f;
    for (int c = 0; c < 32; ++c) {
      sa += Wa[t * 32 + c] * b_lin[c];
      sb += Wb[t * 32 + c] * b_lin[c];
    }
    pre[P_BWA + t] = sa;
    pre[P_BWB + t] = sb;
  }
  if (t == 0) {
    float s = 0.f;
    for (int c = 0; c < 32; ++c) s += W_att[c] * b_lin[c];
    pre[P_C0] = s;
  }
  __syncthreads();
  for (int i = t; i < 1024; i += 256) {
    int p_ = i >> 6, d = i & 63;
    float sl = 0.f, sn = 0.f;
    for (int o = 0; o < 16; ++o) {
      sl += Wl[p_ * 16 + o] * pre[P_WBL + o * 64 + d];
      sn += Wn[p_ * 16 + o] * pre[P_WAL + o * 64 + d];
    }
    pre[P_WLBL + i] = sl;
    pre[P_WNAL + i] = sn;
  }
  if (t < 16) {
    float sl = 0.f, sn = 0.f;
    for (int o = 0; o < 16; ++o) {
      sl += Wl[t * 16 + o] * pre[P_BWB + o];
      sn += Wn[t * 16 + o] * pre[P_BWA + o];
    }
    pre[P_BWL + t] = sl;
    pre[P_BWN + t] = sn;
  }
}

// ---------------------------------------------------------------- k1a: R4 structure, 3 blocks/CU cap
__global__ __launch_bounds__(512, 3) void k1a(
    const float* __restrict__ xl_all, const float* __restrict__ pre,
    float* __restrict__ p_small, float* __restrict__ bigI,
    float* __restrict__ bigV) {
  __shared__ __align__(16) float xaggi[128 * 68];   // f32, pad 68
  __shared__ f32x4 scratch5[5][8][16];              // per-m, per-wave inter partials
  __shared__ float pe[5][8];
  __shared__ float xagg_inter[5][64];

  const int t = threadIdx.x;
  const int b = blockIdx.x;
  const int lane = t & 63;
  const int w = t >> 6;                 // 8 waves; wave owns rows 16w..16w+15
  const int q = lane >> 4;              // row offset within group of 4
  const int i16 = lane & 15;            // d-chunk (4 floats)

  const float* xl = xl_all + (size_t)b * (5 * 128 * 64);
  const f32x4 weff4 = ((const f32x4*)(pre + P_WEFF))[i16];
  const float c0 = pre[P_C0];

  // row(k) = 16w + 4k + q; float offset = row*64 + 4*i16
  const float* xb = xl + (size_t)(16 * w + q) * 64 + 4 * i16;

  f32x4 xA[4], xB[4], acc[4];
  float Zk[4];
  #pragma unroll
  for (int k = 0; k < 4; ++k) {
    acc[k] = (f32x4)0.f;
    Zk[k] = 0.f;
    xA[k] = *(const f32x4*)(xb + k * 256);
  }

  #pragma unroll
  for (int m = 0; m < 5; ++m) {
    f32x4* xc = (m & 1) ? xB : xA;
    f32x4* xn = (m & 1) ? xA : xB;
    if (m < 4) {
      const float* np = xb + (size_t)(m + 1) * 8192;
      #pragma unroll
      for (int k = 0; k < 4; ++k) xn[k] = *(const f32x4*)(np + k * 256);
    }
    // row dots: partial dot4 then butterfly over the 16-lane group
    float a0, a1, a2, a3;
    {
      f32x4 p0 = xc[0] * weff4, p1 = xc[1] * weff4, p2 = xc[2] * weff4, p3 = xc[3] * weff4;
      a0 = p0.x + p0.y + p0.z + p0.w;
      a1 = p1.x + p1.y + p1.z + p1.w;
      a2 = p2.x + p2.y + p2.z + p2.w;
      a3 = p3.x + p3.y + p3.z + p3.w;
    }
    #pragma unroll
    for (int mask = 1; mask <= 8; mask <<= 1) {
      a0 += __shfl_xor(a0, mask);
      a1 += __shfl_xor(a1, mask);
      a2 += __shfl_xor(a2, mask);
      a3 += __shfl_xor(a3, mask);
    }
    float e0 = __expf(a0 + c0), e1 = __expf(a1 + c0);
    float e2 = __expf(a2 + c0), e3 = __expf(a3 + c0);
    Zk[0] += e0; Zk[1] += e1; Zk[2] += e2; Zk[3] += e3;
    f32x4 pim;
    {
      f32x4 pr0 = e0 * xc[0];
      f32x4 pr1 = e1 * xc[1];
      f32x4 pr2 = e2 * xc[2];
      f32x4 pr3 = e3 * xc[3];
      acc[0] += pr0; acc[1] += pr1; acc[2] += pr2; acc[3] += pr3;
      pim = pr0 + pr1 + pr2 + pr3;
    }
    float se = e0 + e1 + e2 + e3;
    #pragma unroll
    for (int mask = 16; mask <= 32; mask <<= 1) {
      pim.x += __shfl_xor(pim.x, mask);
      pim.y += __shfl_xor(pim.y, mask);
      pim.z += __shfl_xor(pim.z, mask);
      pim.w += __shfl_xor(pim.w, mask);
      se += __shfl_xor(se, mask);
    }
    if (lane < 16) {
      scratch5[m][w][i16] = pim;
      if (i16 == 0) pe[m][w] = se;
    }
  }

  // normalize intra rows (thread-local) and write LDS copy
  #pragma unroll
  for (int k = 0; k < 4; ++k) {
    float invz = 1.f / Zk[k];
    f32x4 v = acc[k] * invz;
    int r = 16 * w + 4 * k + q;
    *(f32x4*)&xaggi[r * 68 + 4 * i16] = v;
  }
  __syncthreads();

  // combine inter aggregates across waves, normalize
  if (t < 320) {
    int mm = t >> 6, d = t & 63;
    const float* sp = (const float*)&scratch5[mm][0][0];
    float s = 0.f;
    #pragma unroll
    for (int j = 0; j < 8; ++j) s += sp[j * 64 + d];
    float sume = pe[mm][0] + pe[mm][1] + pe[mm][2] + pe[mm][3] +
                 pe[mm][4] + pe[mm][5] + pe[mm][6] + pe[mm][7];
    xagg_inter[mm][d] = s / sume;
  }
  __syncthreads();

  // phase 2a: per-s projections (intra2 -> bigI, v_intra -> bigV)
  {
    const int q2 = __builtin_amdgcn_readfirstlane(t >> 7);   // 0..3, wave-uniform
    const int s2 = t & 127;
    const float* Wbase = pre + ((q2 < 2) ? P_WBL : P_WLBL) + (q2 & 1) * 512;
    const float* xrow = &xaggi[s2 * 68];
    float acc2[8];
    #pragma unroll
    for (int r = 0; r < 8; ++r) acc2[r] = 0.f;
    #pragma unroll
    for (int c = 0; c < 64; c += 4) {
      f32x4 xa = *(const f32x4*)(xrow + c);
      #pragma unroll
      for (int r = 0; r < 8; ++r)
        acc2[r] += xa.x * Wbase[r * 64 + c] + xa.y * Wbase[r * 64 + c + 1] +
                   xa.z * Wbase[r * 64 + c + 2] + xa.w * Wbase[r * 64 + c + 3];
    }
    const int bb = ((q2 < 2) ? P_BWB : P_BWL) + (q2 & 1) * 8;
    float* dst = ((q2 < 2) ? bigI : bigV) + (size_t)b * 2048 + s2 * 16 + (q2 & 1) * 8;
    f32x4 o0, o1;
    o0.x = acc2[0] + pre[bb + 0];
    o0.y = acc2[1] + pre[bb + 1];
    o0.z = acc2[2] + pre[bb + 2];
    o0.w = acc2[3] + pre[bb + 3];
    o1.x = acc2[4] + pre[bb + 4];
    o1.y = acc2[5] + pre[bb + 5];
    o1.z = acc2[6] + pre[bb + 6];
    o1.w = acc2[7] + pre[bb + 7];
    *(f32x4*)dst = o0;
    *(f32x4*)(dst + 4) = o1;
  }

  // tiny inter projections: inter2[5][16], v_inter[5][16]
  if (t < 160) {
    int o2 = t & 31, mm = t >> 5;
    const float* wr = pre + ((o2 < 16) ? (P_WAL + o2 * 64) : (P_WNAL + (o2 - 16) * 64));
    float p = 0.f;
    #pragma unroll
    for (int d = 0; d < 64; ++d) p += wr[d] * xagg_inter[mm][d];
    p += (o2 < 16) ? pre[P_BWA + o2] : pre[P_BWN + (o2 - 16)];
    float* os = p_small + (size_t)b * 160;
    if (o2 < 16) os[mm * 16 + o2] = p;
    else os[80 + mm * 16 + (o2 - 16)] = p;
  }
}

// ---------------------------------------------------------------- k1b: attention + feat(bf16) + BN partials (R4 structure)
__global__ __launch_bounds__(128, 1) void k1b(
    const float* __restrict__ xg_all, const float* __restrict__ Wc_g,
    const float* __restrict__ Wd_g, const float* __restrict__ p_small,
    const float* __restrict__ bigI, const float* __restrict__ bigV,
    unsigned int* __restrict__ feat16, float* __restrict__ bn_part) {
  __shared__ f32x4 slabI[128][4];
  __shared__ f32x4 slabV[128][4];
  __shared__ float part1[2][32];
  __shared__ float part2[2][32];

  const int t = threadIdx.x;             // = n
  const int b = blockIdx.x;
  const int lane = t & 63;
  const int w = t >> 6;
  const int kmap = ((lane & 1) << 4) | ((lane & 2) << 2) | (lane & 4) |
                   ((lane >> 2) & 2) | ((lane >> 4) & 1);

  // stage I/V slabs (16 KB, coalesced)
  const f32x4* gI = (const f32x4*)(bigI + (size_t)b * 2048);
  const f32x4* gV = (const f32x4*)(bigV + (size_t)b * 2048);
  #pragma unroll
  for (int j = 0; j < 4; ++j) {
    ((f32x4*)slabI)[t + 128 * j] = gI[t + 128 * j];
    ((f32x4*)slabV)[t + 128 * j] = gV[t + 128 * j];
  }

  // xlog[n][0..15] = Wc . xg[n]
  const f32x4* xgr = (const f32x4*)(xg_all + ((size_t)b * 128 + t) * 32);
  f32x4 xv[8];
  #pragma unroll
  for (int j = 0; j < 8; ++j) xv[j] = xgr[j];
  f32x4 xl4[4];
  #pragma unroll
  for (int o4 = 0; o4 < 4; ++o4) {
    f32x4 r;
    #pragma unroll
    for (int jj = 0; jj < 4; ++jj) {
      const int o = o4 * 4 + jj;
      f32x4 s = (f32x4)0.f;
      #pragma unroll
      for (int j = 0; j < 8; ++j) s += xv[j] * *(const f32x4*)(Wc_g + o * 32 + 4 * j);
      r[jj] = s.x + s.y + s.z + s.w;
    }
    xl4[o4] = r;
  }
  __syncthreads();

  // f_intra: 128-way softmax-weighted sum (no max-sub; logits O(10))
  float sum = 0.f;
  f32x4 fa[4];
  #pragma unroll
  for (int j = 0; j < 4; ++j) fa[j] = (f32x4)0.f;
  for (int i = 0; i < 128; ++i) {
    f32x4 d4 = xl4[0] * slabI[i][0] + xl4[1] * slabI[i][1] +
               xl4[2] * slabI[i][2] + xl4[3] * slabI[i][3];
    float e = __expf(d4.x + d4.y + d4.z + d4.w);
    sum += e;
    #pragma unroll
    for (int j = 0; j < 4; ++j) fa[j] += e * slabV[i][j];
  }
  const float inv = 1.f / sum;
  f32x4 fin[4];
  #pragma unroll
  for (int j = 0; j < 4; ++j) fin[j] = fa[j] * inv;

  // f_inter: 5-way softmax
  const float* sm = p_small + (size_t)b * 160;
  float L[5], mx3 = -1e30f;
  #pragma unroll
  for (int mm = 0; mm < 5; ++mm) {
    float p = 0.f;
    #pragma unroll
    for (int o4 = 0; o4 < 4; ++o4) {
      #pragma unroll
      for (int jj = 0; jj < 4; ++jj) p += xl4[o4][jj] * sm[mm * 16 + o4 * 4 + jj];
    }
    L[mm] = p;
    mx3 = fmaxf(mx3, p);
  }
  float sum3 = 0.f;
  #pragma unroll
  for (int mm = 0; mm < 5; ++mm) { L[mm] = __expf(L[mm] - mx3); sum3 += L[mm]; }
  const float inv3 = 1.f / sum3;
  f32x4 fi[4];
  #pragma unroll
  for (int o4 = 0; o4 < 4; ++o4) {
    f32x4 r;
    #pragma unroll
    for (int jj = 0; jj < 4; ++jj) {
      float p = 0.f;
      #pragma unroll
      for (int mm = 0; mm < 5; ++mm) p += L[mm] * sm[80 + mm * 16 + o4 * 4 + jj];
      r[jj] = p * inv3;
    }
    fi[o4] = r;
  }

  // feat[o] = Wd[o][0:16].fi + Wd[o][16:32].fin
  f32x4 feat[8];
  #pragma unroll
  for (int o4 = 0; o4 < 8; ++o4) {
    f32x4 r;
    #pragma unroll
    for (int jj = 0; jj < 4; ++jj) {
      const int o = o4 * 4 + jj;
      f32x4 s = (f32x4)0.f;
      #pragma unroll
      for (int j = 0; j < 4; ++j) {
        s += fi[j]  * *(const f32x4*)(Wd_g + o * 32 + 4 * j);
        s += fin[j] * *(const f32x4*)(Wd_g + o * 32 + 16 + 4 * j);
      }
      r[jj] = s.x + s.y + s.z + s.w;
    }
    feat[o4] = r;
  }
  // write feat as bf16 (16 uints = 64 B per thread, contiguous)
  {
    unsigned int* op = feat16 + ((size_t)b * 128 + t) * 16;
    uint4 u0, u1, u2, u3;
    u0.x = pack2bf(feat[0].x, feat[0].y); u0.y = pack2bf(feat[0].z, feat[0].w);
    u0.z = pack2bf(feat[1].x, feat[1].y); u0.w = pack2bf(feat[1].z, feat[1].w);
    u1.x = pack2bf(feat[2].x, feat[2].y); u1.y = pack2bf(feat[2].z, feat[2].w);
    u1.z = pack2bf(feat[3].x, feat[3].y); u1.w = pack2bf(feat[3].z, feat[3].w);
    u2.x = pack2bf(feat[4].x, feat[4].y); u2.y = pack2bf(feat[4].z, feat[4].w);
    u2.z = pack2bf(feat[5].x, feat[5].y); u2.w = pack2bf(feat[5].z, feat[5].w);
    u3.x = pack2bf(feat[6].x, feat[6].y); u3.y = pack2bf(feat[6].z, feat[6].w);
    u3.z = pack2bf(feat[7].x, feat[7].y); u3.w = pack2bf(feat[7].z, feat[7].w);
    ((uint4*)op)[0] = u0;
    ((uint4*)op)[1] = u1;
    ((uint4*)op)[2] = u2;
    ((uint4*)op)[3] = u3;
  }

  // BN partials: two 32-value butterfly reductions over 64 lanes (f32 feat)
  {
    float a[32];
    #pragma unroll
    for (int o = 0; o < 32; ++o) a[o] = feat[o >> 2][o & 3];
    BSTAGE(1, 16) BSTAGE(2, 8) BSTAGE(4, 4) BSTAGE(8, 2) BSTAGE(16, 1)
    a[0] += __shfl_xor(a[0], 32);
    if (lane < 32) part1[w][kmap] = a[0];
  }
  {
    float a[32];
    #pragma unroll
    for (int o = 0; o < 32; ++o) { float v = feat[o >> 2][o & 3]; a[o] = v * v; }
    BSTAGE(1, 16) BSTAGE(2, 8) BSTAGE(4, 4) BSTAGE(8, 2) BSTAGE(16, 1)
    a[0] += __shfl_xor(a[0], 32);
    if (lane < 32) part2[w][kmap] = a[0];
  }
  __syncthreads();
  if (t < 64) {
    int c = t & 31, h = t >> 5;
    float v = h ? (part2[0][c] + part2[1][c]) : (part1[0][c] + part1[1][c]);
    bn_part[(size_t)b * 64 + h * 32 + c] = v;
  }
}

// ---------------------------------------------------------------- k2: BN coefficients (one block per channel)
__global__ __launch_bounds__(256, 1) void k2_stats(const float* __restrict__ bn_part,
                                                   const float* __restrict__ gamma,
                                                   const float* __restrict__ beta,
                                                   float* __restrict__ coef) {
  __shared__ float red[2][4];
  const int c = blockIdx.x;              // 0..31
  const int t = threadIdx.x;
  const int lane = t & 63, w = t >> 6;
  float s1 = 0.f, s2 = 0.f;
  for (int bb = t; bb < NB; bb += 256) {
    s1 += bn_part[(size_t)bb * 64 + c];
    s2 += bn_part[(size_t)bb * 64 + c + 32];
  }
  #pragma unroll
  for (int mask = 1; mask <= 32; mask <<= 1) {
    s1 += __shfl_xor(s1, mask);
    s2 += __shfl_xor(s2, mask);
  }
  if (lane == 0) { red[0][w] = s1; red[1][w] = s2; }
  __syncthreads();
  if (t == 0) {
    float S1 = red[0][0] + red[0][1] + red[0][2] + red[0][3];
    float S2 = red[1][0] + red[1][1] + red[1][2] + red[1][3];
    const float inv = 1.f / (float)(NB * 128);
    float mean = S1 * inv;
    float var = S2 * inv - mean * mean;
    float scl = gamma[c] * rsqrtf(var + 1e-5f);
    coef[c] = scl;
    coef[32 + c] = beta[c] - mean * scl;
  }
}

// ---------------------------------------------------------------- k3: BN apply + residual + leaky (bf16 feat -> f32 out)
__global__ __launch_bounds__(256) void k3_final(const float* __restrict__ xg,
                                                const unsigned int* __restrict__ feat16,
                                                float* __restrict__ out,
                                                const float* __restrict__ coef) {
  __shared__ float s_c[64];
  if (threadIdx.x < 64) s_c[threadIdx.x] = coef[threadIdx.x];
  __syncthreads();
  size_t i4 = (size_t)blockIdx.x * 256 + threadIdx.x;  // covers 4 channels
  uint2 fu = ((const uint2*)feat16)[i4];
  float4 x = ((const float4*)xg)[i4];
  int c = (int)((i4 * 4) & 31);
  float4 r;
  r.x = x.x + bflo(fu.x) * s_c[c + 0] + s_c[32 + c + 0];
  r.y = x.y + bfhi(fu.x) * s_c[c + 1] + s_c[32 + c + 1];
  r.z = x.z + bflo(fu.y) * s_c[c + 2] + s_c[32 + c + 2];
  r.w = x.w + bfhi(fu.y) * s_c[c + 3] + s_c[32 + c + 3];
  r.x = r.x >= 0.f ? r.x : 0.2f * r.x;
  r.y = r.y >= 0.f ? r.y : 0.2f * r.y;
  r.z = r.z >= 0.f ? r.z : 0.2f * r.z;
  r.w = r.w >= 0.f ? r.w : 0.2f * r.w;
  ((float4*)out)[i4] = r;
}

// ----------------------------------------------------------------
extern "C" void kernel_launch(void* const* d_in, const int* in_sizes, int n_in,
                              void* d_out, int out_size, void* d_ws, size_t ws_size,
                              hipStream_t stream) {
  const float* xg    = (const float*)d_in[0];
  const float* xl    = (const float*)d_in[1];
  const float* W_lin = (const float*)d_in[2];
  const float* b_lin = (const float*)d_in[3];
  const float* W_att = (const float*)d_in[4];
  const float* Wa    = (const float*)d_in[5];
  const float* Wb    = (const float*)d_in[6];
  const float* Wc    = (const float*)d_in[7];
  const float* Wn    = (const float*)d_in[8];
  const float* Wl    = (const float*)d_in[9];
  const float* Wd    = (const float*)d_in[10];
  const float* gamma = (const float*)d_in[11];
  const float* beta  = (const float*)d_in[12];
  float* out = (float*)d_out;
  float* ws = (float*)d_ws;
  float* pre = ws;
  float* bn_part = ws + WS_BNPART;
  float* coef = ws + WS_COEF;
  float* p_small = ws + WS_SMALL;
  float* bigI = ws + WS_BIG_I;
  float* bigV = ws + WS_BIG_V;
  unsigned int* feat16 = (unsigned int*)(ws + WS_FEAT16);

  hipLaunchKernelGGL(k0_pre, dim3(1), dim3(256), 0, stream,
                     W_lin, b_lin, W_att, Wa, Wb, Wn, Wl, pre);
  hipLaunchKernelGGL(k1a, dim3(NB), dim3(512), 0, stream, xl, pre, p_small, bigI, bigV);
  hipLaunchKernelGGL(k1b, dim3(NB), dim3(128), 0, stream,
                     xg, Wc, Wd, p_small, bigI, bigV, feat16, bn_part);
  hipLaunchKernelGGL(k2_stats, dim3(32), dim3(256), 0, stream, bn_part, gamma, beta, coef);
  hipLaunchKernelGGL(k3_final, dim3(8192), dim3(256), 0, stream, xg, feat16, out, coef);
}

// Round 10
// 196.669 us; speedup vs baseline: 1.7064x; 1.0043x over previous
//
#include <hip/hip_runtime.h>
#include <math.h>

#define NB 2048
typedef float f32x4 __attribute__((ext_vector_type(4)));
typedef float f32x2 __attribute__((ext_vector_type(2)));

// pre[] float offsets (folded weights)
#define P_WAL 0
#define P_WBL 1024
#define P_WLBL 2048
#define P_WNAL 3072
#define P_WEFF 4096
#define P_BWA 4160
#define P_BWB 4176
#define P_BWL 4192
#define P_BWN 4208
#define P_C0  4224

// ws float offsets
#define WS_BNPART 4352
#define WS_COEF   135424
#define WS_SMALL  135488                  // [2048][160]
#define WS_BIG_I  463168                  // [2048][2048] f32: intra2T rows [s][16]
#define WS_BIG_V  (463168 + 4194304)      // [2048][2048] f32: v_intra rows [s][16]
#define WS_FEAT16 (463168 + 8388608)      // [2048][128][32] bf16

__device__ __forceinline__ unsigned short f2bf(float f) {
  unsigned int u = __float_as_uint(f);
  u += 0x7fffu + ((u >> 16) & 1u);
  return (unsigned short)(u >> 16);
}
__device__ __forceinline__ unsigned int pack2bf(float lo, float hi) {
  return (unsigned int)f2bf(lo) | ((unsigned int)f2bf(hi) << 16);
}
__device__ __forceinline__ float bflo(unsigned int u) { return __uint_as_float(u << 16); }
__device__ __forceinline__ float bfhi(unsigned int u) { return __uint_as_float(u & 0xffff0000u); }

// segmented butterfly: reduces a[HALF*2] over lanes, halving regs per stage
#define BSTAGE(MASK, HALF)                                        \
  { const bool hi_ = (lane & (MASK)) != 0;                        \
    _Pragma("unroll")                                             \
    for (int k_ = 0; k_ < (HALF); ++k_) {                         \
      float mine_ = hi_ ? a[k_ + (HALF)] : a[k_];                 \
      float oth_  = hi_ ? a[k_] : a[k_ + (HALF)];                 \
      a[k_] = mine_ + __shfl_xor(oth_, (MASK));                   \
    } }

// ---------------------------------------------------------------- k0: fold weights
__global__ __launch_bounds__(256) void k0_pre(const float* __restrict__ W_lin,
                                              const float* __restrict__ b_lin,
                                              const float* __restrict__ W_att,
                                              const float* __restrict__ Wa,
                                              const float* __restrict__ Wb,
                                              const float* __restrict__ Wn,
                                              const float* __restrict__ Wl,
                                              float* __restrict__ pre) {
  int t = threadIdx.x;
  for (int i = t; i < 1024; i += 256) {
    int o = i >> 6, d = i & 63;
    float sa = 0.f, sb = 0.f;
    for (int c = 0; c < 32; ++c) {
      float wl = W_lin[c * 64 + d];
      sa += Wa[o * 32 + c] * wl;
      sb += Wb[o * 32 + c] * wl;
    }
    pre[P_WAL + i] = sa;
    pre[P_WBL + i] = sb;
  }
  if (t < 64) {
    float s = 0.f;
    for (int c = 0; c < 32; ++c) s += W_att[c] * W_lin[c * 64 + t];
    pre[P_WEFF + t] = s;
  }
  if (t < 16) {
    float sa = 0.f, sb = 0.f;
    for (int c = 0; c < 32; ++c) {
      sa += Wa[t * 32 + c] * b_lin[c];
      sb += Wb[t * 32 + c] * b_lin[c];
    }
    pre[P_BWA + t] = sa;
    pre[P_BWB + t] = sb;
  }
  if (t == 0) {
    float s = 0.f;
    for (int c = 0; c < 32; ++c) s += W_att[c] * b_lin[c];
    pre[P_C0] = s;
  }
  __syncthreads();
  for (int i = t; i < 1024; i += 256) {
    int p_ = i >> 6, d = i & 63;
    float sl = 0.f, sn = 0.f;
    for (int o = 0; o < 16; ++o) {
      sl += Wl[p_ * 16 + o] * pre[P_WBL + o * 64 + d];
      sn += Wn[p_ * 16 + o] * pre[P_WAL + o * 64 + d];
    }
    pre[P_WLBL + i] = sl;
    pre[P_WNAL + i] = sn;
  }
  if (t < 16) {
    float sl = 0.f, sn = 0.f;
    for (int o = 0; o < 16; ++o) {
      sl += Wl[t * 16 + o] * pre[P_BWB + o];
      sn += Wn[t * 16 + o] * pre[P_BWA + o];
    }
    pre[P_BWL + t] = sl;
    pre[P_BWN + t] = sn;
  }
}

// ---------------------------------------------------------------- k1a: 1024 threads, 2 rows/thread, VGPR<=64 -> 32 waves/CU
__global__ __launch_bounds__(1024, 2) void k1a(
    const float* __restrict__ xl_all, const float* __restrict__ pre,
    float* __restrict__ p_small, float* __restrict__ bigI,
    float* __restrict__ bigV) {
  __shared__ __align__(16) float xaggi[128 * 68];   // 34816 B
  __shared__ f32x4 scratch5[5][16][16];             // 20480 B: per-m per-wave inter partials
  __shared__ float pe[5][16];
  __shared__ float xagg_inter[5][64];

  const int t = threadIdx.x;
  const int b = blockIdx.x;
  const int lane = t & 63;
  const int w = t >> 6;                 // 16 waves; wave owns rows 8w..8w+7
  const int q = lane >> 4;              // row offset within group of 4
  const int i16 = lane & 15;            // d-chunk (4 floats)

  const float* xl = xl_all + (size_t)b * (5 * 128 * 64);
  const f32x4 weff4 = ((const f32x4*)(pre + P_WEFF))[i16];
  const float c0 = pre[P_C0];

  // row(k) = 8w + 4k + q (k in 0..1); float offset = row*64 + 4*i16
  const float* xb = xl + (size_t)(8 * w + q) * 64 + 4 * i16;

  f32x4 xA[2], xB[2], acc[2];
  float Zk[2];
  #pragma unroll
  for (int k = 0; k < 2; ++k) {
    acc[k] = (f32x4)0.f;
    Zk[k] = 0.f;
    xA[k] = *(const f32x4*)(xb + k * 256);
  }

  #pragma unroll
  for (int m = 0; m < 5; ++m) {
    f32x4* xc = (m & 1) ? xB : xA;
    f32x4* xn = (m & 1) ? xA : xB;
    if (m < 4) {
      const float* np = xb + (size_t)(m + 1) * 8192;
      #pragma unroll
      for (int k = 0; k < 2; ++k) xn[k] = *(const f32x4*)(np + k * 256);
    }
    // row dots: partial dot4 then butterfly over the 16-lane group
    float a0, a1;
    {
      f32x4 p0 = xc[0] * weff4, p1 = xc[1] * weff4;
      a0 = p0.x + p0.y + p0.z + p0.w;
      a1 = p1.x + p1.y + p1.z + p1.w;
    }
    #pragma unroll
    for (int mask = 1; mask <= 8; mask <<= 1) {
      a0 += __shfl_xor(a0, mask);
      a1 += __shfl_xor(a1, mask);
    }
    float e0 = __expf(a0 + c0), e1 = __expf(a1 + c0);
    Zk[0] += e0; Zk[1] += e1;
    f32x4 pim;
    {
      f32x4 pr0 = e0 * xc[0];
      f32x4 pr1 = e1 * xc[1];
      acc[0] += pr0; acc[1] += pr1;
      pim = pr0 + pr1;
    }
    float se = e0 + e1;
    #pragma unroll
    for (int mask = 16; mask <= 32; mask <<= 1) {
      pim.x += __shfl_xor(pim.x, mask);
      pim.y += __shfl_xor(pim.y, mask);
      pim.z += __shfl_xor(pim.z, mask);
      pim.w += __shfl_xor(pim.w, mask);
      se += __shfl_xor(se, mask);
    }
    if (lane < 16) {
      scratch5[m][w][i16] = pim;
      if (i16 == 0) pe[m][w] = se;
    }
  }

  // normalize intra rows (thread-local) and write LDS copy
  #pragma unroll
  for (int k = 0; k < 2; ++k) {
    float invz = 1.f / Zk[k];
    f32x4 v = acc[k] * invz;
    int r = 8 * w + 4 * k + q;
    *(f32x4*)&xaggi[r * 68 + 4 * i16] = v;
  }
  __syncthreads();

  // combine inter aggregates across 16 waves, normalize
  if (t < 320) {
    int mm = t >> 6, d = t & 63;
    const float* sp = (const float*)&scratch5[mm][0][0];
    float s = 0.f;
    #pragma unroll
    for (int j = 0; j < 16; ++j) s += sp[j * 64 + d];
    float sume = 0.f;
    #pragma unroll
    for (int j = 0; j < 16; ++j) sume += pe[mm][j];
    xagg_inter[mm][d] = s / sume;
  }
  __syncthreads();

  // phase 2a: per-s projections (threads 0..511)
  if (t < 512) {
    const int q2 = __builtin_amdgcn_readfirstlane(t >> 7);   // 0..3, wave-uniform
    const int s2 = t & 127;
    const float* Wbase = pre + ((q2 < 2) ? P_WBL : P_WLBL) + (q2 & 1) * 512;
    const float* xrow = &xaggi[s2 * 68];
    float acc2[8];
    #pragma unroll
    for (int r = 0; r < 8; ++r) acc2[r] = 0.f;
    #pragma unroll
    for (int c = 0; c < 64; c += 4) {
      f32x4 xa = *(const f32x4*)(xrow + c);
      #pragma unroll
      for (int r = 0; r < 8; ++r)
        acc2[r] += xa.x * Wbase[r * 64 + c] + xa.y * Wbase[r * 64 + c + 1] +
                   xa.z * Wbase[r * 64 + c + 2] + xa.w * Wbase[r * 64 + c + 3];
    }
    const int bb = ((q2 < 2) ? P_BWB : P_BWL) + (q2 & 1) * 8;
    float* dst = ((q2 < 2) ? bigI : bigV) + (size_t)b * 2048 + s2 * 16 + (q2 & 1) * 8;
    f32x4 o0, o1;
    o0.x = acc2[0] + pre[bb + 0];
    o0.y = acc2[1] + pre[bb + 1];
    o0.z = acc2[2] + pre[bb + 2];
    o0.w = acc2[3] + pre[bb + 3];
    o1.x = acc2[4] + pre[bb + 4];
    o1.y = acc2[5] + pre[bb + 5];
    o1.z = acc2[6] + pre[bb + 6];
    o1.w = acc2[7] + pre[bb + 7];
    *(f32x4*)dst = o0;
    *(f32x4*)(dst + 4) = o1;
  } else if (t < 672) {
    // tiny inter projections: inter2[5][16], v_inter[5][16]
    int tt = t - 512;
    int o2 = tt & 31, mm = tt >> 5;
    const float* wr = pre + ((o2 < 16) ? (P_WAL + o2 * 64) : (P_WNAL + (o2 - 16) * 64));
    float p = 0.f;
    #pragma unroll
    for (int d = 0; d < 64; ++d) p += wr[d] * xagg_inter[mm][d];
    p += (o2 < 16) ? pre[P_BWA + o2] : pre[P_BWN + (o2 - 16)];
    float* os = p_small + (size_t)b * 160;
    if (o2 < 16) os[mm * 16 + o2] = p;
    else os[80 + mm * 16 + (o2 - 16)] = p;
  }
}

// ---------------------------------------------------------------- k1b: attention + feat(bf16) + BN partials (R4-proven)
__global__ __launch_bounds__(128, 1) void k1b(
    const float* __restrict__ xg_all, const float* __restrict__ Wc_g,
    const float* __restrict__ Wd_g, const float* __restrict__ p_small,
    const float* __restrict__ bigI, const float* __restrict__ bigV,
    unsigned int* __restrict__ feat16, float* __restrict__ bn_part) {
  __shared__ f32x4 slabI[128][4];
  __shared__ f32x4 slabV[128][4];
  __shared__ float part1[2][32];
  __shared__ float part2[2][32];

  const int t = threadIdx.x;             // = n
  const int b = blockIdx.x;
  const int lane = t & 63;
  const int w = t >> 6;
  const int kmap = ((lane & 1) << 4) | ((lane & 2) << 2) | (lane & 4) |
                   ((lane >> 2) & 2) | ((lane >> 4) & 1);

  // stage I/V slabs (16 KB, coalesced)
  const f32x4* gI = (const f32x4*)(bigI + (size_t)b * 2048);
  const f32x4* gV = (const f32x4*)(bigV + (size_t)b * 2048);
  #pragma unroll
  for (int j = 0; j < 4; ++j) {
    ((f32x4*)slabI)[t + 128 * j] = gI[t + 128 * j];
    ((f32x4*)slabV)[t + 128 * j] = gV[t + 128 * j];
  }

  // xlog[n][0..15] = Wc . xg[n]
  const f32x4* xgr = (const f32x4*)(xg_all + ((size_t)b * 128 + t) * 32);
  f32x4 xv[8];
  #pragma unroll
  for (int j = 0; j < 8; ++j) xv[j] = xgr[j];
  f32x4 xl4[4];
  #pragma unroll
  for (int o4 = 0; o4 < 4; ++o4) {
    f32x4 r;
    #pragma unroll
    for (int jj = 0; jj < 4; ++jj) {
      const int o = o4 * 4 + jj;
      f32x4 s = (f32x4)0.f;
      #pragma unroll
      for (int j = 0; j < 8; ++j) s += xv[j] * *(const f32x4*)(Wc_g + o * 32 + 4 * j);
      r[jj] = s.x + s.y + s.z + s.w;
    }
    xl4[o4] = r;
  }
  __syncthreads();

  // f_intra: 128-way softmax-weighted sum (no max-sub; logits O(10))
  float sum = 0.f;
  f32x4 fa[4];
  #pragma unroll
  for (int j = 0; j < 4; ++j) fa[j] = (f32x4)0.f;
  for (int i = 0; i < 128; ++i) {
    f32x4 d4 = xl4[0] * slabI[i][0] + xl4[1] * slabI[i][1] +
               xl4[2] * slabI[i][2] + xl4[3] * slabI[i][3];
    float e = __expf(d4.x + d4.y + d4.z + d4.w);
    sum += e;
    #pragma unroll
    for (int j = 0; j < 4; ++j) fa[j] += e * slabV[i][j];
  }
  const float inv = 1.f / sum;
  f32x4 fin[4];
  #pragma unroll
  for (int j = 0; j < 4; ++j) fin[j] = fa[j] * inv;

  // f_inter: 5-way softmax
  const float* sm = p_small + (size_t)b * 160;
  float L[5], mx3 = -1e30f;
  #pragma unroll
  for (int mm = 0; mm < 5; ++mm) {
    float p = 0.f;
    #pragma unroll
    for (int o4 = 0; o4 < 4; ++o4) {
      #pragma unroll
      for (int jj = 0; jj < 4; ++jj) p += xl4[o4][jj] * sm[mm * 16 + o4 * 4 + jj];
    }
    L[mm] = p;
    mx3 = fmaxf(mx3, p);
  }
  float sum3 = 0.f;
  #pragma unroll
  for (int mm = 0; mm < 5; ++mm) { L[mm] = __expf(L[mm] - mx3); sum3 += L[mm]; }
  const float inv3 = 1.f / sum3;
  f32x4 fi[4];
  #pragma unroll
  for (int o4 = 0; o4 < 4; ++o4) {
    f32x4 r;
    #pragma unroll
    for (int jj = 0; jj < 4; ++jj) {
      float p = 0.f;
      #pragma unroll
      for (int mm = 0; mm < 5; ++mm) p += L[mm] * sm[80 + mm * 16 + o4 * 4 + jj];
      r[jj] = p * inv3;
    }
    fi[o4] = r;
  }

  // feat[o] = Wd[o][0:16].fi + Wd[o][16:32].fin
  f32x4 feat[8];
  #pragma unroll
  for (int o4 = 0; o4 < 8; ++o4) {
    f32x4 r;
    #pragma unroll
    for (int jj = 0; jj < 4; ++jj) {
      const int o = o4 * 4 + jj;
      f32x4 s = (f32x4)0.f;
      #pragma unroll
      for (int j = 0; j < 4; ++j) {
        s += fi[j]  * *(const f32x4*)(Wd_g + o * 32 + 4 * j);
        s += fin[j] * *(const f32x4*)(Wd_g + o * 32 + 16 + 4 * j);
      }
      r[jj] = s.x + s.y + s.z + s.w;
    }
    feat[o4] = r;
  }
  // write feat as bf16 (64 B per thread, contiguous)
  {
    unsigned int* op = feat16 + ((size_t)b * 128 + t) * 16;
    uint4 u0, u1, u2, u3;
    u0.x = pack2bf(feat[0].x, feat[0].y); u0.y = pack2bf(feat[0].z, feat[0].w);
    u0.z = pack2bf(feat[1].x, feat[1].y); u0.w = pack2bf(feat[1].z, feat[1].w);
    u1.x = pack2bf(feat[2].x, feat[2].y); u1.y = pack2bf(feat[2].z, feat[2].w);
    u1.z = pack2bf(feat[3].x, feat[3].y); u1.w = pack2bf(feat[3].z, feat[3].w);
    u2.x = pack2bf(feat[4].x, feat[4].y); u2.y = pack2bf(feat[4].z, feat[4].w);
    u2.z = pack2bf(feat[5].x, feat[5].y); u2.w = pack2bf(feat[5].z, feat[5].w);
    u3.x = pack2bf(feat[6].x, feat[6].y); u3.y = pack2bf(feat[6].z, feat[6].w);
    u3.z = pack2bf(feat[7].x, feat[7].y); u3.w = pack2bf(feat[7].z, feat[7].w);
    ((uint4*)op)[0] = u0;
    ((uint4*)op)[1] = u1;
    ((uint4*)op)[2] = u2;
    ((uint4*)op)[3] = u3;
  }

  // BN partials: two 32-value butterfly reductions over 64 lanes (f32 feat)
  {
    float a[32];
    #pragma unroll
    for (int o = 0; o < 32; ++o) a[o] = feat[o >> 2][o & 3];
    BSTAGE(1, 16) BSTAGE(2, 8) BSTAGE(4, 4) BSTAGE(8, 2) BSTAGE(16, 1)
    a[0] += __shfl_xor(a[0], 32);
    if (lane < 32) part1[w][kmap] = a[0];
  }
  {
    float a[32];
    #pragma unroll
    for (int o = 0; o < 32; ++o) { float v = feat[o >> 2][o & 3]; a[o] = v * v; }
    BSTAGE(1, 16) BSTAGE(2, 8) BSTAGE(4, 4) BSTAGE(8, 2) BSTAGE(16, 1)
    a[0] += __shfl_xor(a[0], 32);
    if (lane < 32) part2[w][kmap] = a[0];
  }
  __syncthreads();
  if (t < 64) {
    int c = t & 31, h = t >> 5;
    float v = h ? (part2[0][c] + part2[1][c]) : (part1[0][c] + part1[1][c]);
    bn_part[(size_t)b * 64 + h * 32 + c] = v;
  }
}

// ---------------------------------------------------------------- k2: BN coefficients (one block per channel)
__global__ __launch_bounds__(256, 1) void k2_stats(const float* __restrict__ bn_part,
                                                   const float* __restrict__ gamma,
                                                   const float* __restrict__ beta,
                                                   float* __restrict__ coef) {
  __shared__ float red[2][4];
  const int c = blockIdx.x;              // 0..31
  const int t = threadIdx.x;
  const int lane = t & 63, w = t >> 6;
  float s1 = 0.f, s2 = 0.f;
  for (int bb = t; bb < NB; bb += 256) {
    s1 += bn_part[(size_t)bb * 64 + c];
    s2 += bn_part[(size_t)bb * 64 + c + 32];
  }
  #pragma unroll
  for (int mask = 1; mask <= 32; mask <<= 1) {
    s1 += __shfl_xor(s1, mask);
    s2 += __shfl_xor(s2, mask);
  }
  if (lane == 0) { red[0][w] = s1; red[1][w] = s2; }
  __syncthreads();
  if (t == 0) {
    float S1 = red[0][0] + red[0][1] + red[0][2] + red[0][3];
    float S2 = red[1][0] + red[1][1] + red[1][2] + red[1][3];
    const float inv = 1.f / (float)(NB * 128);
    float mean = S1 * inv;
    float var = S2 * inv - mean * mean;
    float scl = gamma[c] * rsqrtf(var + 1e-5f);
    coef[c] = scl;
    coef[32 + c] = beta[c] - mean * scl;
  }
}

// ---------------------------------------------------------------- k3: BN apply + residual + leaky (bf16 feat -> f32 out)
__global__ __launch_bounds__(256) void k3_final(const float* __restrict__ xg,
                                                const unsigned int* __restrict__ feat16,
                                                float* __restrict__ out,
                                                const float* __restrict__ coef) {
  __shared__ float s_c[64];
  if (threadIdx.x < 64) s_c[threadIdx.x] = coef[threadIdx.x];
  __syncthreads();
  size_t i4 = (size_t)blockIdx.x * 256 + threadIdx.x;  // covers 4 channels
  uint2 fu = ((const uint2*)feat16)[i4];
  float4 x = ((const float4*)xg)[i4];
  int c = (int)((i4 * 4) & 31);
  float4 r;
  r.x = x.x + bflo(fu.x) * s_c[c + 0] + s_c[32 + c + 0];
  r.y = x.y + bfhi(fu.x) * s_c[c + 1] + s_c[32 + c + 1];
  r.z = x.z + bflo(fu.y) * s_c[c + 2] + s_c[32 + c + 2];
  r.w = x.w + bfhi(fu.y) * s_c[c + 3] + s_c[32 + c + 3];
  r.x = r.x >= 0.f ? r.x : 0.2f * r.x;
  r.y = r.y >= 0.f ? r.y : 0.2f * r.y;
  r.z = r.z >= 0.f ? r.z : 0.2f * r.z;
  r.w = r.w >= 0.f ? r.w : 0.2f * r.w;
  ((float4*)out)[i4] = r;
}

// ----------------------------------------------------------------
extern "C" void kernel_launch(void* const* d_in, const int* in_sizes, int n_in,
                              void* d_out, int out_size, void* d_ws, size_t ws_size,
                              hipStream_t stream) {
  const float* xg    = (const float*)d_in[0];
  const float* xl    = (const float*)d_in[1];
  const float* W_lin = (const float*)d_in[2];
  const float* b_lin = (const float*)d_in[3];
  const float* W_att = (const float*)d_in[4];
  const float* Wa    = (const float*)d_in[5];
  const float* Wb    = (const float*)d_in[6];
  const float* Wc    = (const float*)d_in[7];
  const float* Wn    = (const float*)d_in[8];
  const float* Wl    = (const float*)d_in[9];
  const float* Wd    = (const float*)d_in[10];
  const float* gamma = (const float*)d_in[11];
  const float* beta  = (const float*)d_in[12];
  float* out = (float*)d_out;
  float* ws = (float*)d_ws;
  float* pre = ws;
  float* bn_part = ws + WS_BNPART;
  float* coef = ws + WS_COEF;
  float* p_small = ws + WS_SMALL;
  float* bigI = ws + WS_BIG_I;
  float* bigV = ws + WS_BIG_V;
  unsigned int* feat16 = (unsigned int*)(ws + WS_FEAT16);

  hipLaunchKernelGGL(k0_pre, dim3(1), dim3(256), 0, stream,
                     W_lin, b_lin, W_att, Wa, Wb, Wn, Wl, pre);
  hipLaunchKernelGGL(k1a, dim3(NB), dim3(1024), 0, stream, xl, pre, p_small, bigI, bigV);
  hipLaunchKernelGGL(k1b, dim3(NB), dim3(128), 0, stream,
                     xg, Wc, Wd, p_small, bigI, bigV, feat16, bn_part);
  hipLaunchKernelGGL(k2_stats, dim3(32), dim3(256), 0, stream, bn_part, gamma, beta, coef);
  hipLaunchKernelGGL(k3_final, dim3(8192), dim3(256), 0, stream, xg, feat16, out, coef);
}